// Round 1
// baseline (1177.815 us; speedup 1.0000x reference)
//
#include <hip/hip_runtime.h>
#include <hip/hip_bf16.h>

// Problem constants (fixed shapes from setup_inputs)
#define CD    384      // DIM
#define NTOK  4096     // N = 64*64
#define NKV   1024     // Nk = 32*32
#define BB    4        // batch
#define NHD   8        // heads
#define HDD   48       // head dim
#define LOG2E 1.4426950408889634f

// ---------------- workspace layout (float element offsets) ----------------
#define OFF_FLAG 0
#define OFF_XC   16
#define OFF_WQ   (OFF_XC + 6291456)
#define OFF_WK   (OFF_WQ + 147456)
#define OFF_WV   (OFF_WK + 147456)
#define OFF_WP   (OFF_WV + 147456)
#define OFF_SRW  (OFF_WP + 147456)
#define OFF_BP   (OFF_SRW + 1536)
#define OFF_SRB  (OFF_BP + 384)
#define OFF_GA   (OFF_SRB + 384)
#define OFF_BE   (OFF_GA + 384)
#define OFF_MU   (OFF_BE + 384)
#define OFF_VA   (OFF_MU + 384)
#define OFF_XK   (OFF_VA + 384)
#define OFF_K    (OFF_XK + 1572864)
#define OFF_V    (OFF_K + 1572864)
#define OFF_Q    (OFF_V + 1572864)   // q buffer; aliased as attention output
// total floats = OFF_Q + 6291456 = 17,895,184  (~71.6 MB)

static __device__ __forceinline__ float bf_lo(unsigned v){ return __uint_as_float(v << 16); }
static __device__ __forceinline__ float bf_hi(unsigned v){ return __uint_as_float(v & 0xFFFF0000u); }
static __device__ __forceinline__ float bfu(unsigned short u){ return __uint_as_float(((unsigned)u) << 16); }
static __device__ __forceinline__ unsigned short f2bf(float f){
  unsigned u = __float_as_uint(f);
  u += 0x7FFFu + ((u >> 16) & 1u);     // round-to-nearest-even
  return (unsigned short)(u >> 16);
}

// ---------------- dtype detection ----------------
// If inputs are packed bf16, the low 16 bits of each dword are a bf16 value of
// N(0,1) data -> exponent field (bits 14..7) concentrated in [118,137].
// If fp32, those bits are uniform mantissa bits (hit prob ~8%).
__global__ void detect_bf16(const unsigned* __restrict__ xraw, int* __restrict__ flag){
  unsigned w = xraw[threadIdx.x];
  unsigned e = (w >> 7) & 0xFFu;
  unsigned long long m = __ballot(e >= 118u && e <= 137u);
  if (threadIdx.x == 0) *flag = (__popcll(m) >= 40) ? 1 : 0;
}

static __device__ __forceinline__ float cvt_elem(const void* p, int i, bool bf){
  if (bf) return bfu(((const unsigned short*)p)[i]);
  return ((const float*)p)[i];
}

// canonicalize every input (except relative_pos) to fp32 in ws
__global__ __launch_bounds__(256) void convert_all(
    const void* x, const void* wq, const void* wk, const void* wv, const void* wp,
    const void* bp, const void* srw, const void* srb, const void* ga, const void* be,
    const void* mu, const void* va, float* ws){
  const bool bf = ((const int*)ws)[OFF_FLAG] != 0;
  int idx = blockIdx.x * 256 + threadIdx.x;
  if (idx < 6291456) { ws[OFF_XC + idx] = cvt_elem(x, idx, bf); return; }
  idx -= 6291456;
  if (idx < 147456) { ws[OFF_WQ + idx] = cvt_elem(wq, idx, bf); return; }
  idx -= 147456;
  if (idx < 147456) { ws[OFF_WK + idx] = cvt_elem(wk, idx, bf); return; }
  idx -= 147456;
  if (idx < 147456) { ws[OFF_WV + idx] = cvt_elem(wv, idx, bf); return; }
  idx -= 147456;
  if (idx < 147456) { ws[OFF_WP + idx] = cvt_elem(wp, idx, bf); return; }
  idx -= 147456;
  if (idx < 1536) { ws[OFF_SRW + idx] = cvt_elem(srw, idx, bf); return; }
  idx -= 1536;
  if (idx < 384) { ws[OFF_BP + idx] = cvt_elem(bp, idx, bf); return; }
  idx -= 384;
  if (idx < 384) { ws[OFF_SRB + idx] = cvt_elem(srb, idx, bf); return; }
  idx -= 384;
  if (idx < 384) { ws[OFF_GA + idx] = cvt_elem(ga, idx, bf); return; }
  idx -= 384;
  if (idx < 384) { ws[OFF_BE + idx] = cvt_elem(be, idx, bf); return; }
  idx -= 384;
  if (idx < 384) { ws[OFF_MU + idx] = cvt_elem(mu, idx, bf); return; }
  idx -= 384;
  ws[OFF_VA + idx] = cvt_elem(va, idx, bf);
}

// ---------------- depthwise conv 2x2 stride 2 + BatchNorm(eval) -> xk[B,Nk,C] ----------------
__global__ __launch_bounds__(256) void sr_bn(const float* __restrict__ xc,
    const float* __restrict__ srw, const float* __restrict__ srb,
    const float* __restrict__ ga, const float* __restrict__ be,
    const float* __restrict__ mu, const float* __restrict__ va,
    float* __restrict__ xk){
  int idx = blockIdx.x * 256 + threadIdx.x;          // 1,572,864 elements
  int c  = idx % CD;
  int nk = (idx / CD) & (NKV - 1);
  int b  = idx / (CD * NKV);
  int i = nk >> 5, j = nk & 31;                       // output spatial (i,j) in 32x32
  const float* xb = xc + ((long)(b * NTOK + i * 128 + j * 2)) * CD + c;   // row (2i)*64 + 2j
  float acc = xb[0]        * srw[c*4+0]
            + xb[CD]       * srw[c*4+1]
            + xb[64*CD]    * srw[c*4+2]
            + xb[65*CD]    * srw[c*4+3];
  float inv = rsqrtf(va[c] + 1e-5f) * ga[c];
  xk[idx] = (acc + srb[c] - mu[c]) * inv + be[c];
}

// ---------------- fp32 GEMM: C[m][o] = sum_i A[m][i]*W[o][i] (+bias), K=N=384 ----------------
// 128x128 tile, BK=16, 256 threads, 8x8 per thread (split 4+4 rows/cols for
// conflict-free LDS reads: 16 lanes * b128 at stride 16B covers 64 consecutive
// floats -> exactly 2-way bank aliasing = free).
__global__ __launch_bounds__(256) void gemm384(const float* A, const float* W,
    const float* bias, void* Cout, const int* bfflag){
  __shared__ float As[16][132];
  __shared__ float Bs[16][132];
  const int tid = threadIdx.x;
  const int m0 = blockIdx.y * 128, n0 = blockIdx.x * 128;
  const int rg = tid >> 4, cg = tid & 15;
  const int lrow = tid >> 2, lk = (tid & 3) * 4;
  float acc[8][8];
  #pragma unroll
  for (int i = 0; i < 8; ++i)
    #pragma unroll
    for (int j = 0; j < 8; ++j) acc[i][j] = 0.f;

  for (int kt = 0; kt < CD; kt += 16) {
    float4 a0 = *(const float4*)&A[(long)(m0 + lrow)      * CD + kt + lk];
    float4 a1 = *(const float4*)&A[(long)(m0 + 64 + lrow) * CD + kt + lk];
    float4 w0 = *(const float4*)&W[(long)(n0 + lrow)      * CD + kt + lk];
    float4 w1 = *(const float4*)&W[(long)(n0 + 64 + lrow) * CD + kt + lk];
    __syncthreads();   // previous iteration's LDS reads done
    As[lk+0][lrow]=a0.x; As[lk+1][lrow]=a0.y; As[lk+2][lrow]=a0.z; As[lk+3][lrow]=a0.w;
    As[lk+0][64+lrow]=a1.x; As[lk+1][64+lrow]=a1.y; As[lk+2][64+lrow]=a1.z; As[lk+3][64+lrow]=a1.w;
    Bs[lk+0][lrow]=w0.x; Bs[lk+1][lrow]=w0.y; Bs[lk+2][lrow]=w0.z; Bs[lk+3][lrow]=w0.w;
    Bs[lk+0][64+lrow]=w1.x; Bs[lk+1][64+lrow]=w1.y; Bs[lk+2][64+lrow]=w1.z; Bs[lk+3][64+lrow]=w1.w;
    __syncthreads();
    #pragma unroll
    for (int k = 0; k < 16; ++k) {
      float4 av0 = *(const float4*)&As[k][rg*4];
      float4 av1 = *(const float4*)&As[k][64 + rg*4];
      float4 wv0 = *(const float4*)&Bs[k][cg*4];
      float4 wv1 = *(const float4*)&Bs[k][64 + cg*4];
      float a_[8] = {av0.x,av0.y,av0.z,av0.w,av1.x,av1.y,av1.z,av1.w};
      float w_[8] = {wv0.x,wv0.y,wv0.z,wv0.w,wv1.x,wv1.y,wv1.z,wv1.w};
      #pragma unroll
      for (int i = 0; i < 8; ++i)
        #pragma unroll
        for (int j = 0; j < 8; ++j)
          acc[i][j] = fmaf(a_[i], w_[j], acc[i][j]);
    }
  }

  const bool bf = bfflag && (*bfflag != 0);
  #pragma unroll
  for (int i = 0; i < 8; ++i) {
    int row = m0 + ((i < 4) ? (rg*4 + i) : (64 + rg*4 + i - 4));
    #pragma unroll
    for (int half = 0; half < 2; ++half) {
      int col = n0 + half*64 + cg*4;
      float4 v;
      v.x = acc[i][half*4+0]; v.y = acc[i][half*4+1];
      v.z = acc[i][half*4+2]; v.w = acc[i][half*4+3];
      if (bias) { v.x += bias[col]; v.y += bias[col+1]; v.z += bias[col+2]; v.w += bias[col+3]; }
      if (!bf) {
        *(float4*)((float*)Cout + (long)row * CD + col) = v;
      } else {
        ushort4 u; u.x=f2bf(v.x); u.y=f2bf(v.y); u.z=f2bf(v.z); u.w=f2bf(v.w);
        *(ushort4*)((unsigned short*)Cout + (long)row * CD + col) = u;
      }
    }
  }
}

// ---------------- fused flash attention ----------------
// grid (32, 8, 4) = (n-tile, head, batch); 256 threads.
// Block: 128 q-rows, m-tiles of 64 over Nk=1024, online softmax.
// tn = tid>>4 (16 groups x 8 rows), tm = tid&15 (4 score cols / 3 out dims).
// Row state (max, sumexp, alpha) replicated across the 16 tm lanes -> alpha is
// lane-uniform, so O rescale needs no communication. P goes through LDS (bf16).
__global__ __launch_bounds__(256) void attn_fused(const float* qb, const float* kb,
    const float* vb, const void* rel, const int* flag, float* outp){
  const int nb = blockIdx.x, h = blockIdx.y, b = blockIdx.z;
  const int n0 = nb * 128;
  const int tid = threadIdx.x;
  const int tn = tid >> 4, tm = tid & 15;

  __shared__ float          Qs[48][128];   // [d][n] fp32   24,576 B
  __shared__ unsigned short Ks[48][72];    // [d][m] bf16    6,912 B
  __shared__ unsigned short Vs[64][52];    // [m][d] bf16    6,656 B
  __shared__ unsigned short Ps[64][136];   // [m][n] bf16   17,408 B   (total 55,552 B)

  // stage Q tile once: 128 rows x 48 floats
  #pragma unroll
  for (int it = 0; it < 6; ++it) {
    int f = tid + it * 256;
    int row = f / 12, dq = f % 12;
    float4 qv = *(const float4*)&qb[((long)(b * NTOK + n0 + row)) * CD + h * HDD + dq * 4];
    Qs[dq*4+0][row]=qv.x; Qs[dq*4+1][row]=qv.y; Qs[dq*4+2][row]=qv.z; Qs[dq*4+3][row]=qv.w;
  }

  float m_run[8], l_run[8], o_acc[8][3];
  #pragma unroll
  for (int i = 0; i < 8; ++i) {
    m_run[i] = -1e30f; l_run[i] = 0.f;
    o_acc[i][0]=0.f; o_acc[i][1]=0.f; o_acc[i][2]=0.f;
  }
  const float sc = 0.14433756729740643f;   // 48^-0.5
  const bool bfm = (*flag != 0);
  const float*          relf = (const float*)rel;
  const unsigned short* relh = (const unsigned short*)rel;
  const long relbase = ((long)h * NTOK + n0) * NKV;

  for (int t = 0; t < 16; ++t) {
    // global->reg staging of K,V tiles (64 rows x 48)
    float4 kv[3], vv[3];
    #pragma unroll
    for (int i = 0; i < 3; ++i) {
      int f = tid + i * 256;
      int mr = f / 12, dq = f % 12;
      long base = ((long)(b * NKV + t * 64 + mr)) * CD + h * HDD + dq * 4;
      kv[i] = *(const float4*)&kb[base];
      vv[i] = *(const float4*)&vb[base];
    }
    __syncthreads();   // prior iter's LDS reads (Ks,Vs,Ps) complete
    #pragma unroll
    for (int i = 0; i < 3; ++i) {
      int f = tid + i * 256;
      int mr = f / 12, dq = f % 12;
      Ks[dq*4+0][mr] = f2bf(kv[i].x);
      Ks[dq*4+1][mr] = f2bf(kv[i].y);
      Ks[dq*4+2][mr] = f2bf(kv[i].z);
      Ks[dq*4+3][mr] = f2bf(kv[i].w);
      uint2 pk;
      pk.x = (unsigned)f2bf(vv[i].x) | ((unsigned)f2bf(vv[i].y) << 16);
      pk.y = (unsigned)f2bf(vv[i].z) | ((unsigned)f2bf(vv[i].w) << 16);
      *(uint2*)&Vs[mr][dq*4] = pk;
    }
    __syncthreads();

    // S = Q*K^T  (8 rows x 4 cols per thread)
    float s[8][4];
    #pragma unroll
    for (int i = 0; i < 8; ++i) { s[i][0]=0.f; s[i][1]=0.f; s[i][2]=0.f; s[i][3]=0.f; }
    #pragma unroll 8
    for (int d = 0; d < 48; ++d) {
      float4 qa = *(const float4*)&Qs[d][tn*8];
      float4 qc = *(const float4*)&Qs[d][tn*8+4];
      uint2 kk = *(const uint2*)&Ks[d][tm*4];
      float k0 = bf_lo(kk.x), k1 = bf_hi(kk.x), k2 = bf_lo(kk.y), k3 = bf_hi(kk.y);
      float qv[8] = {qa.x,qa.y,qa.z,qa.w,qc.x,qc.y,qc.z,qc.w};
      #pragma unroll
      for (int i = 0; i < 8; ++i) {
        s[i][0] = fmaf(qv[i], k0, s[i][0]);
        s[i][1] = fmaf(qv[i], k1, s[i][1]);
        s[i][2] = fmaf(qv[i], k2, s[i][2]);
        s[i][3] = fmaf(qv[i], k3, s[i][3]);
      }
    }

    // scale + relative-position bias, per-row partial max
    float pmax[8];
    #pragma unroll
    for (int i = 0; i < 8; ++i) {
      long ro = relbase + (long)(tn*8 + i) * NKV + t*64 + tm*4;
      float r0, r1, r2, r3;
      if (!bfm) {
        float4 rr = *(const float4*)&relf[ro];
        r0 = rr.x; r1 = rr.y; r2 = rr.z; r3 = rr.w;
      } else {
        uint2 rb = *(const uint2*)&relh[ro];
        r0 = bf_lo(rb.x); r1 = bf_hi(rb.x); r2 = bf_lo(rb.y); r3 = bf_hi(rb.y);
      }
      s[i][0] = fmaf(s[i][0], sc, r0);
      s[i][1] = fmaf(s[i][1], sc, r1);
      s[i][2] = fmaf(s[i][2], sc, r2);
      s[i][3] = fmaf(s[i][3], sc, r3);
      pmax[i] = fmaxf(fmaxf(s[i][0], s[i][1]), fmaxf(s[i][2], s[i][3]));
    }
    // row max across the 16 tm lanes
    #pragma unroll
    for (int off = 1; off < 16; off <<= 1)
      #pragma unroll
      for (int i = 0; i < 8; ++i)
        pmax[i] = fmaxf(pmax[i], __shfl_xor(pmax[i], off, 64));

    float al[8];
    #pragma unroll
    for (int i = 0; i < 8; ++i) {
      float nm = fmaxf(m_run[i], pmax[i]);
      al[i] = exp2f((m_run[i] - nm) * LOG2E);
      m_run[i] = nm;
    }
    #pragma unroll
    for (int i = 0; i < 8; ++i) {
      float p0 = exp2f((s[i][0] - m_run[i]) * LOG2E);
      float p1 = exp2f((s[i][1] - m_run[i]) * LOG2E);
      float p2 = exp2f((s[i][2] - m_run[i]) * LOG2E);
      float p3 = exp2f((s[i][3] - m_run[i]) * LOG2E);
      l_run[i] = l_run[i] * al[i] + (p0 + p1 + p2 + p3);
      s[i][0]=p0; s[i][1]=p1; s[i][2]=p2; s[i][3]=p3;
      o_acc[i][0]*=al[i]; o_acc[i][1]*=al[i]; o_acc[i][2]*=al[i];
    }
    // write P (bf16) transposed [m][n]: one b128 per column j (8 consecutive rows)
    #pragma unroll
    for (int j = 0; j < 4; ++j) {
      uint4 w;
      w.x = (unsigned)f2bf(s[0][j]) | ((unsigned)f2bf(s[1][j]) << 16);
      w.y = (unsigned)f2bf(s[2][j]) | ((unsigned)f2bf(s[3][j]) << 16);
      w.z = (unsigned)f2bf(s[4][j]) | ((unsigned)f2bf(s[5][j]) << 16);
      w.w = (unsigned)f2bf(s[6][j]) | ((unsigned)f2bf(s[7][j]) << 16);
      *(uint4*)&Ps[tm*4 + j][tn*8] = w;
    }
    __syncthreads();

    // O += P @ V   (8 rows x 3 dims per thread)
    #pragma unroll 4
    for (int mm = 0; mm < 64; ++mm) {
      uint4 pw = *(const uint4*)&Ps[mm][tn*8];
      float p[8] = { bf_lo(pw.x), bf_hi(pw.x), bf_lo(pw.y), bf_hi(pw.y),
                     bf_lo(pw.z), bf_hi(pw.z), bf_lo(pw.w), bf_hi(pw.w) };
      float v0 = bfu(Vs[mm][tm*3+0]);
      float v1 = bfu(Vs[mm][tm*3+1]);
      float v2 = bfu(Vs[mm][tm*3+2]);
      #pragma unroll
      for (int r = 0; r < 8; ++r) {
        o_acc[r][0] = fmaf(p[r], v0, o_acc[r][0]);
        o_acc[r][1] = fmaf(p[r], v1, o_acc[r][1]);
        o_acc[r][2] = fmaf(p[r], v2, o_acc[r][2]);
      }
    }
  }

  // final sumexp reduce across tm lanes, normalize, store
  #pragma unroll
  for (int off = 1; off < 16; off <<= 1)
    #pragma unroll
    for (int i = 0; i < 8; ++i)
      l_run[i] += __shfl_xor(l_run[i], off, 64);
  #pragma unroll
  for (int i = 0; i < 8; ++i) {
    float inv = 1.0f / l_run[i];
    long rowb = ((long)(b * NTOK + n0 + tn*8 + i)) * CD + h * HDD + tm*3;
    outp[rowb+0] = o_acc[i][0] * inv;
    outp[rowb+1] = o_acc[i][1] * inv;
    outp[rowb+2] = o_acc[i][2] * inv;
  }
}

extern "C" void kernel_launch(void* const* d_in, const int* in_sizes, int n_in,
                              void* d_out, int out_size, void* d_ws, size_t ws_size,
                              hipStream_t stream) {
  // d_in: 0=x 1=relative_pos 2=H 3=W 4=Wq 5=Wk 6=Wv 7=Wp 8=bp 9=sr_w 10=sr_b
  //       11=bn_gamma 12=bn_beta 13=bn_mean 14=bn_var
  float* ws   = (float*)d_ws;
  int*   flag = (int*)d_ws;
  float* xc   = ws + OFF_XC;
  float* xk   = ws + OFF_XK;
  float* kbuf = ws + OFF_K;
  float* vbuf = ws + OFF_V;
  float* qbuf = ws + OFF_Q;   // also attention output (same block owns same region)

  detect_bf16<<<1, 64, 0, stream>>>((const unsigned*)d_in[0], flag);
  convert_all<<<26895, 256, 0, stream>>>(d_in[0], d_in[4], d_in[5], d_in[6], d_in[7],
      d_in[8], d_in[9], d_in[10], d_in[11], d_in[12], d_in[13], d_in[14], ws);
  sr_bn<<<6144, 256, 0, stream>>>(xc, ws + OFF_SRW, ws + OFF_SRB,
      ws + OFF_GA, ws + OFF_BE, ws + OFF_MU, ws + OFF_VA, xk);
  gemm384<<<dim3(3, 128), 256, 0, stream>>>(xc, ws + OFF_WQ, nullptr, qbuf, nullptr);
  gemm384<<<dim3(3, 32),  256, 0, stream>>>(xk, ws + OFF_WK, nullptr, kbuf, nullptr);
  gemm384<<<dim3(3, 32),  256, 0, stream>>>(xk, ws + OFF_WV, nullptr, vbuf, nullptr);
  attn_fused<<<dim3(32, 8, 4), 256, 0, stream>>>(qbuf, kbuf, vbuf, d_in[1], flag, qbuf);
  gemm384<<<dim3(3, 128), 256, 0, stream>>>(qbuf, ws + OFF_WP, ws + OFF_BP, d_out, flag);
}

// Round 2
// 446.360 us; speedup vs baseline: 2.6387x; 2.6387x over previous
//
#include <hip/hip_runtime.h>
#include <hip/hip_bf16.h>

#define LOG2E 1.4426950408889634f

typedef short bf16x8 __attribute__((ext_vector_type(8)));
typedef float f32x4  __attribute__((ext_vector_type(4)));

// ---------------- workspace layout ----------------
// float region (offsets in floats from d_ws)
#define OFF_BPf  16
#define OFF_SRWf (OFF_BPf + 384)
#define OFF_SRBf (OFF_SRWf + 1536)
#define OFF_GAf  (OFF_SRBf + 384)
#define OFF_BEf  (OFF_GAf + 384)
#define OFF_MUf  (OFF_BEf + 384)
#define OFF_VAf  (OFF_MUf + 384)            // ends at float 3856 (byte 15424, 16B-aligned)
// bf16 region (offsets in ushorts from d_ws)
#define U_XB 7712
#define U_WQ (U_XB + 6291456)
#define U_WK (U_WQ + 147456)
#define U_WV (U_WK + 147456)
#define U_WP (U_WV + 147456)
#define U_XK (U_WP + 147456)
#define U_QB (U_XK + 1572864)
#define U_KB (U_QB + 6291456)
#define U_VT (U_KB + 1572864)   // V transposed: [b,h,48,1024]
#define U_OB (U_VT + 1572864)   // attention output [b,n,384]
// total = 24,190,496 ushorts ~= 48.4 MB

static __device__ __forceinline__ float bfu(unsigned short u){ return __uint_as_float(((unsigned)u) << 16); }
static __device__ __forceinline__ unsigned short f2bf(float f){
  unsigned u = __float_as_uint(f);
  u += 0x7FFFu + ((u >> 16) & 1u);      // RNE
  return (unsigned short)(u >> 16);
}

// ---------------- dtype detection (bf16-packed vs fp32 inputs) ----------------
__global__ void detect_bf16(const unsigned* __restrict__ xraw, int* __restrict__ flag){
  unsigned w = xraw[threadIdx.x];
  unsigned e = (w >> 7) & 0xFFu;        // exponent of the LOW 16-bit half if bf16-packed
  unsigned long long m = __ballot(e >= 118u && e <= 137u);
  if (threadIdx.x == 0) *flag = (__popcll(m) >= 40) ? 1 : 0;
}

static __device__ __forceinline__ float cvtf(const void* p, int i, bool bf){
  return bf ? bfu(((const unsigned short*)p)[i]) : ((const float*)p)[i];
}
static __device__ __forceinline__ unsigned short cvtb(const void* p, int i, bool bf){
  return bf ? ((const unsigned short*)p)[i] : f2bf(((const float*)p)[i]);
}

// canonicalize: big tensors -> bf16, small vectors -> fp32
__global__ __launch_bounds__(256) void convert_all(
    const void* x, const void* wq, const void* wk, const void* wv, const void* wp,
    const void* bp, const void* srw, const void* srb, const void* ga, const void* be,
    const void* mu, const void* va, float* ws){
  const bool bf = ((const int*)ws)[0] != 0;
  unsigned short* u = (unsigned short*)ws;
  int idx = blockIdx.x * 256 + threadIdx.x;
  if (idx < 6291456){ u[U_XB+idx] = cvtb(x, idx, bf); return; }   idx -= 6291456;
  if (idx < 147456) { u[U_WQ+idx] = cvtb(wq, idx, bf); return; }  idx -= 147456;
  if (idx < 147456) { u[U_WK+idx] = cvtb(wk, idx, bf); return; }  idx -= 147456;
  if (idx < 147456) { u[U_WV+idx] = cvtb(wv, idx, bf); return; }  idx -= 147456;
  if (idx < 147456) { u[U_WP+idx] = cvtb(wp, idx, bf); return; }  idx -= 147456;
  if (idx < 1536)   { ws[OFF_SRWf+idx] = cvtf(srw, idx, bf); return; } idx -= 1536;
  if (idx < 384)    { ws[OFF_BPf+idx]  = cvtf(bp,  idx, bf); return; } idx -= 384;
  if (idx < 384)    { ws[OFF_SRBf+idx] = cvtf(srb, idx, bf); return; } idx -= 384;
  if (idx < 384)    { ws[OFF_GAf+idx]  = cvtf(ga,  idx, bf); return; } idx -= 384;
  if (idx < 384)    { ws[OFF_BEf+idx]  = cvtf(be,  idx, bf); return; } idx -= 384;
  if (idx < 384)    { ws[OFF_MUf+idx]  = cvtf(mu,  idx, bf); return; } idx -= 384;
  if (idx < 384)    { ws[OFF_VAf+idx]  = cvtf(va,  idx, bf); }
}

// ---------------- depthwise conv 2x2 s2 + BN(eval) -> xk bf16 [B,1024,384] ----------------
__global__ __launch_bounds__(256) void sr_bn(const unsigned short* __restrict__ xb,
    const float* __restrict__ wsf, unsigned short* __restrict__ xkb){
  int idx = blockIdx.x * 256 + threadIdx.x;       // 1,572,864
  int c  = idx % 384;
  int nk = (idx / 384) & 1023;
  int b  = idx / (384 * 1024);
  int i = nk >> 5, j = nk & 31;
  const unsigned short* xp = xb + ((size_t)(b*4096 + i*128 + j*2))*384 + c;
  float acc = bfu(xp[0])      * wsf[OFF_SRWf + c*4 + 0]
            + bfu(xp[384])    * wsf[OFF_SRWf + c*4 + 1]
            + bfu(xp[64*384]) * wsf[OFF_SRWf + c*4 + 2]
            + bfu(xp[65*384]) * wsf[OFF_SRWf + c*4 + 3];
  float inv = rsqrtf(wsf[OFF_VAf + c] + 1e-5f) * wsf[OFF_GAf + c];
  float r = (acc + wsf[OFF_SRBf + c] - wsf[OFF_MUf + c]) * inv + wsf[OFF_BEf + c];
  xkb[idx] = f2bf(r);
}

// ---------------- MFMA GEMM: C[m][o] = sum_i A[m][i] * W[o][i] ----------------
// 128x128 tile, BK=32, 256 thr (4 waves in 2x2), 16x16x32 bf16 MFMA.
// mode 0: bf16 out [M][384]; mode 1: final out (fp32 or bf16 by *flag) + bias;
// mode 2: V-transpose out vt[(b*8+h)*48+d][1024]+mk.
__global__ __launch_bounds__(256) void gemm_mfma(const unsigned short* __restrict__ A,
    const unsigned short* __restrict__ W, const float* __restrict__ bias,
    void* __restrict__ out, const int* __restrict__ flag, int mode){
  __shared__ unsigned short As[128][40];
  __shared__ unsigned short Ws[128][40];
  const int tid = threadIdx.x;
  const int wave = tid >> 6, lane = tid & 63, lg = lane >> 4, ln = lane & 15;
  const int m0 = blockIdx.y * 128, n0 = blockIdx.x * 128;
  const int wm = (wave >> 1) * 64, wn = (wave & 1) * 64;
  f32x4 acc[4][4];
  #pragma unroll
  for (int i = 0; i < 4; ++i)
    #pragma unroll
    for (int j = 0; j < 4; ++j) acc[i][j] = (f32x4){0.f,0.f,0.f,0.f};

  const int arow = tid >> 1, acol = (tid & 1) * 16;
  for (int kt = 0; kt < 384; kt += 32) {
    uint4 a0 = *(const uint4*)&A[(size_t)(m0+arow)*384 + kt + acol];
    uint4 a1 = *(const uint4*)&A[(size_t)(m0+arow)*384 + kt + acol + 8];
    uint4 w0 = *(const uint4*)&W[(size_t)(n0+arow)*384 + kt + acol];
    uint4 w1 = *(const uint4*)&W[(size_t)(n0+arow)*384 + kt + acol + 8];
    __syncthreads();
    *(uint4*)&As[arow][acol]   = a0;  *(uint4*)&As[arow][acol+8] = a1;
    *(uint4*)&Ws[arow][acol]   = w0;  *(uint4*)&Ws[arow][acol+8] = w1;
    __syncthreads();
    bf16x8 af[4], wf[4];
    #pragma unroll
    for (int mi = 0; mi < 4; ++mi) af[mi] = *(const bf16x8*)&As[wm + mi*16 + ln][lg*8];
    #pragma unroll
    for (int ni = 0; ni < 4; ++ni) wf[ni] = *(const bf16x8*)&Ws[wn + ni*16 + ln][lg*8];
    #pragma unroll
    for (int mi = 0; mi < 4; ++mi)
      #pragma unroll
      for (int ni = 0; ni < 4; ++ni)
        acc[mi][ni] = __builtin_amdgcn_mfma_f32_16x16x32_bf16(af[mi], wf[ni], acc[mi][ni], 0, 0, 0);
  }

  const bool bff = flag && (*flag != 0);
  #pragma unroll
  for (int mi = 0; mi < 4; ++mi)
    #pragma unroll
    for (int ni = 0; ni < 4; ++ni)
      #pragma unroll
      for (int r = 0; r < 4; ++r) {
        int grow = m0 + wm + mi*16 + lg*4 + r;
        int gcol = n0 + wn + ni*16 + ln;
        float v = acc[mi][ni][r];
        if (bias) v += bias[gcol];
        if (mode == 0) {
          ((unsigned short*)out)[(size_t)grow*384 + gcol] = f2bf(v);
        } else if (mode == 1) {
          if (bff) ((unsigned short*)out)[(size_t)grow*384 + gcol] = f2bf(v);
          else     ((float*)out)[(size_t)grow*384 + gcol] = v;
        } else {
          int hh = gcol / 48, d = gcol - hh*48;
          int bb = grow >> 10, mk = grow & 1023;
          ((unsigned short*)out)[((size_t)((bb*8 + hh)*48 + d))*1024 + mk] = f2bf(v);
        }
      }
}

// ---------------- barrier-free MFMA flash attention ----------------
// grid (32, 8, 4) = (q-tile of 128, head, batch); 256 thr = 4 waves, each owns
// 32 q-rows (2 M-tiles). KV tiles of 64 (4 N-tiles, 2 K-steps of mfma x32;
// head dim 48 zero-padded to 64). Q/K/V frags loaded straight from global
// (V pre-transposed), P round-trips through wave-PRIVATE LDS -> no barriers.
__global__ __launch_bounds__(256) void attn_mfma(const unsigned short* __restrict__ qb,
    const unsigned short* __restrict__ kb, const unsigned short* __restrict__ vt,
    const void* __restrict__ rel, const int* __restrict__ flag,
    unsigned short* __restrict__ ob){
  __shared__ unsigned short Ps[128][88];   // stride 88: 16B-aligned rows, low-conflict
  const int nb = blockIdx.x, h = blockIdx.y, b = blockIdx.z;
  const int n0 = nb * 128;
  const int tid = threadIdx.x, wave = tid >> 6, lane = tid & 63;
  const int lg = lane >> 4, ln = lane & 15;
  const int mrow = wave * 32;
  const bool bfm = (*flag != 0);

  // Q fragments (A-layout), dims 48..63 zeroed
  bf16x8 qf[2][2];
  #pragma unroll
  for (int mi = 0; mi < 2; ++mi) {
    const unsigned short* qp = qb + ((size_t)(b*4096 + n0 + mrow + mi*16 + ln))*384 + h*48;
    qf[mi][0] = *(const bf16x8*)(qp + lg*8);
    bf16x8 tmp = {0,0,0,0,0,0,0,0};
    if (lg < 2) tmp = *(const bf16x8*)(qp + 32 + lg*8);
    qf[mi][1] = tmp;
  }

  f32x4 o[2][3];
  float lsum[2][4], mrun[2][4];
  #pragma unroll
  for (int mi = 0; mi < 2; ++mi) {
    #pragma unroll
    for (int nd = 0; nd < 3; ++nd) o[mi][nd] = (f32x4){0.f,0.f,0.f,0.f};
    #pragma unroll
    for (int r = 0; r < 4; ++r) { lsum[mi][r] = 0.f; mrun[mi][r] = -1e30f; }
  }
  const float scl = 0.14433756729740643f * LOG2E;   // scale folded into log2 domain
  const float* relf = (const float*)rel;
  const unsigned short* relh = (const unsigned short*)rel;

  for (int t = 0; t < 16; ++t) {
    // K fragments (B-layout) direct from global
    bf16x8 kf[4][2];
    #pragma unroll
    for (int ni = 0; ni < 4; ++ni) {
      const unsigned short* kp = kb + ((size_t)(b*1024 + t*64 + ni*16 + ln))*384 + h*48;
      kf[ni][0] = *(const bf16x8*)(kp + lg*8);
      bf16x8 tmp = {0,0,0,0,0,0,0,0};
      if (lg < 2) tmp = *(const bf16x8*)(kp + 32 + lg*8);
      kf[ni][1] = tmp;
    }
    // S = Q K^T
    f32x4 s[2][4];
    #pragma unroll
    for (int mi = 0; mi < 2; ++mi)
      #pragma unroll
      for (int ni = 0; ni < 4; ++ni) s[mi][ni] = (f32x4){0.f,0.f,0.f,0.f};
    #pragma unroll
    for (int ks = 0; ks < 2; ++ks)
      #pragma unroll
      for (int mi = 0; mi < 2; ++mi)
        #pragma unroll
        for (int ni = 0; ni < 4; ++ni)
          s[mi][ni] = __builtin_amdgcn_mfma_f32_16x16x32_bf16(qf[mi][ks], kf[ni][ks], s[mi][ni], 0, 0, 0);

    // online softmax in D-layout (row = lg*4+r, col = ni*16+ln), log2 domain
    #pragma unroll
    for (int mi = 0; mi < 2; ++mi) {
      const size_t rb = ((size_t)h*4096 + n0 + mrow + mi*16 + lg*4)*1024 + (size_t)t*64 + ln;
      float rv[4][4];
      if (!bfm) {
        #pragma unroll
        for (int r = 0; r < 4; ++r)
          #pragma unroll
          for (int ni = 0; ni < 4; ++ni) rv[r][ni] = relf[rb + (size_t)r*1024 + ni*16];
      } else {
        #pragma unroll
        for (int r = 0; r < 4; ++r)
          #pragma unroll
          for (int ni = 0; ni < 4; ++ni) rv[r][ni] = bfu(relh[rb + (size_t)r*1024 + ni*16]);
      }
      float pm[4];
      #pragma unroll
      for (int r = 0; r < 4; ++r) {
        #pragma unroll
        for (int ni = 0; ni < 4; ++ni)
          s[mi][ni][r] = fmaf(s[mi][ni][r], scl, rv[r][ni] * LOG2E);
        pm[r] = fmaxf(fmaxf(s[mi][0][r], s[mi][1][r]), fmaxf(s[mi][2][r], s[mi][3][r]));
      }
      #pragma unroll
      for (int off = 1; off < 16; off <<= 1)
        #pragma unroll
        for (int r = 0; r < 4; ++r)
          pm[r] = fmaxf(pm[r], __shfl_xor(pm[r], off, 64));
      #pragma unroll
      for (int r = 0; r < 4; ++r) {
        float mn = fmaxf(mrun[mi][r], pm[r]);
        float al = exp2f(mrun[mi][r] - mn);
        mrun[mi][r] = mn;
        float ps = 0.f;
        #pragma unroll
        for (int ni = 0; ni < 4; ++ni) {
          float p = exp2f(s[mi][ni][r] - mn);
          s[mi][ni][r] = p;
          ps += p;
        }
        lsum[mi][r] = lsum[mi][r] * al + ps;   // lane-partial over owned cols
        #pragma unroll
        for (int nd = 0; nd < 3; ++nd) o[mi][nd][r] *= al;
        int prow = mrow + mi*16 + lg*4 + r;
        #pragma unroll
        for (int ni = 0; ni < 4; ++ni)
          Ps[prow][ni*16 + ln] = f2bf(s[mi][ni][r]);
      }
    }

    // O += P V  (P from wave-private LDS in A-layout; V^T direct from global)
    bf16x8 vf[3][2];
    #pragma unroll
    for (int nd = 0; nd < 3; ++nd)
      #pragma unroll
      for (int ks = 0; ks < 2; ++ks)
        vf[nd][ks] = *(const bf16x8*)(vt + ((size_t)((b*8 + h)*48 + nd*16 + ln))*1024 + t*64 + ks*32 + lg*8);
    #pragma unroll
    for (int mi = 0; mi < 2; ++mi)
      #pragma unroll
      for (int ks = 0; ks < 2; ++ks) {
        bf16x8 pa = *(const bf16x8*)&Ps[mrow + mi*16 + ln][ks*32 + lg*8];
        #pragma unroll
        for (int nd = 0; nd < 3; ++nd)
          o[mi][nd] = __builtin_amdgcn_mfma_f32_16x16x32_bf16(pa, vf[nd][ks], o[mi][nd], 0, 0, 0);
      }
  }

  // finalize: full row-sum of l across the 16-lane group, normalize, store bf16
  #pragma unroll
  for (int off = 1; off < 16; off <<= 1)
    #pragma unroll
    for (int mi = 0; mi < 2; ++mi)
      #pragma unroll
      for (int r = 0; r < 4; ++r)
        lsum[mi][r] += __shfl_xor(lsum[mi][r], off, 64);
  #pragma unroll
  for (int mi = 0; mi < 2; ++mi)
    #pragma unroll
    for (int r = 0; r < 4; ++r) {
      float inv = 1.0f / lsum[mi][r];
      size_t rowb = ((size_t)(b*4096 + n0 + mrow + mi*16 + lg*4 + r))*384 + h*48 + ln;
      #pragma unroll
      for (int nd = 0; nd < 3; ++nd)
        ob[rowb + nd*16] = f2bf(o[mi][nd][r] * inv);
    }
}

extern "C" void kernel_launch(void* const* d_in, const int* in_sizes, int n_in,
                              void* d_out, int out_size, void* d_ws, size_t ws_size,
                              hipStream_t stream) {
  // d_in: 0=x 1=relative_pos 2=H 3=W 4=Wq 5=Wk 6=Wv 7=Wp 8=bp 9=sr_w 10=sr_b
  //       11=bn_gamma 12=bn_beta 13=bn_mean 14=bn_var
  float* ws = (float*)d_ws;
  int* flag = (int*)d_ws;
  unsigned short* u = (unsigned short*)d_ws;

  detect_bf16<<<1, 64, 0, stream>>>((const unsigned*)d_in[0], flag);
  convert_all<<<26895, 256, 0, stream>>>(d_in[0], d_in[4], d_in[5], d_in[6], d_in[7],
      d_in[8], d_in[9], d_in[10], d_in[11], d_in[12], d_in[13], d_in[14], ws);
  sr_bn<<<6144, 256, 0, stream>>>(u + U_XB, ws, u + U_XK);
  gemm_mfma<<<dim3(3, 128), 256, 0, stream>>>(u + U_XB, u + U_WQ, nullptr, u + U_QB, flag, 0);
  gemm_mfma<<<dim3(3, 32),  256, 0, stream>>>(u + U_XK, u + U_WK, nullptr, u + U_KB, flag, 0);
  gemm_mfma<<<dim3(3, 32),  256, 0, stream>>>(u + U_XK, u + U_WV, nullptr, u + U_VT, flag, 2);
  attn_mfma<<<dim3(32, 8, 4), 256, 0, stream>>>(u + U_QB, u + U_KB, u + U_VT, d_in[1], flag, u + U_OB);
  gemm_mfma<<<dim3(3, 128), 256, 0, stream>>>(u + U_OB, u + U_WP, ws + OFF_BPf, d_out, flag, 1);
}